// Round 2
// baseline (327.491 us; speedup 1.0000x reference)
//
#include <hip/hip_runtime.h>
#include <hip/hip_bf16.h>
#include <stdint.h>

// MHA: B=8, N=1024, DIM=768, H=12, D=64.  I/O is FP32; internal compute bf16 MFMA.
#define NH 12

typedef __attribute__((ext_vector_type(8))) short bf16x8;
typedef __attribute__((ext_vector_type(4))) float f32x4;

static __device__ __forceinline__ ushort f2bf(float f) {
  union { float f; uint32_t u; } v; v.f = f;
  uint32_t r = (v.u + 0x7FFFu + ((v.u >> 16) & 1u)) >> 16;
  return (ushort)r;
}

static __device__ __forceinline__ void gl_lds16(const void* g, void* l) {
  __builtin_amdgcn_global_load_lds(
      (const __attribute__((address_space(1))) uint32_t*)(uintptr_t)g,
      (__attribute__((address_space(3))) uint32_t*)(uintptr_t)l,
      16, 0, 0);
}

static __device__ __forceinline__ f32x4 mfma32(bf16x8 a, bf16x8 b, f32x4 c) {
  return __builtin_amdgcn_mfma_f32_16x16x32_bf16(a, b, c, 0, 0, 0);
}

// ---------------- Kernel 0: fp32 -> bf16 convert -------------------------
__global__ __launch_bounds__(256) void k_cvt(const float4* __restrict__ src,
                                             ushort4* __restrict__ dst, int n4) {
  int i = blockIdx.x * blockDim.x + threadIdx.x;
  if (i < n4) {
    float4 v = src[i];
    ushort4 o;
    o.x = f2bf(v.x); o.y = f2bf(v.y); o.z = f2bf(v.z); o.w = f2bf(v.w);
    dst[i] = o;
  }
}

// ---------------- Kernel 1: QKV projection -------------------------------
// C[8192,2304] = X[8192,768] * Wqkv[2304,768]^T, scatter into Q,K,V^T.
// Column c maps to (h,d,which): c = h*192 + d*3 + which  (0=q,1=k,2=v)
__global__ __launch_bounds__(256) void k_qkv(const ushort* __restrict__ X,
                                             const ushort* __restrict__ W,
                                             ushort* __restrict__ Qb,
                                             ushort* __restrict__ Kb,
                                             ushort* __restrict__ Vt) {
  __shared__ __align__(16) ushort As[128 * 32];
  __shared__ __align__(16) ushort Bs[128 * 32];
  const int m0 = blockIdx.y * 128;
  const int n0 = blockIdx.x * 128;
  const int tid = threadIdx.x;
  const int w = tid >> 6, l = tid & 63, g = l >> 4, c15 = l & 15;
  const int wm = w >> 1, wn = w & 1;

  f32x4 acc[4][4] = {};

  const int soff = w * 1024 + l * 16;   // byte offset within 8KB tile (inst 0)
  const int e0 = soff >> 1;
  const int row0 = e0 >> 5, col0 = e0 & 31;
  const int e1 = (soff + 4096) >> 1;
  const int row1 = e1 >> 5, col1 = e1 & 31;

  for (int k0 = 0; k0 < 768; k0 += 32) {
    gl_lds16(X + (size_t)(m0 + row0) * 768 + k0 + col0, (char*)As + soff);
    gl_lds16(X + (size_t)(m0 + row1) * 768 + k0 + col1, (char*)As + soff + 4096);
    gl_lds16(W + (size_t)(n0 + row0) * 768 + k0 + col0, (char*)Bs + soff);
    gl_lds16(W + (size_t)(n0 + row1) * 768 + k0 + col1, (char*)Bs + soff + 4096);
    __syncthreads();
    bf16x8 af[4], bfr[4];
#pragma unroll
    for (int i = 0; i < 4; i++) {
      af[i]  = *(const bf16x8*)&As[(wm * 64 + i * 16 + c15) * 32 + g * 8];
      bfr[i] = *(const bf16x8*)&Bs[(wn * 64 + i * 16 + c15) * 32 + g * 8];
    }
#pragma unroll
    for (int mr = 0; mr < 4; mr++)
#pragma unroll
      for (int nr = 0; nr < 4; nr++)
        acc[mr][nr] = mfma32(af[mr], bfr[nr], acc[mr][nr]);
    __syncthreads();
  }

  // Epilogue: C/D layout col = lane&15, row = (lane>>4)*4 + r  [m89 verified]
#pragma unroll
  for (int nr = 0; nr < 4; nr++) {
    const int cc = n0 + wn * 64 + nr * 16 + c15;
    const int hd = cc / 3;
    const int which = cc - hd * 3;
    const int d = hd & 63, h = hd >> 6;
#pragma unroll
    for (int mr = 0; mr < 4; mr++) {
      const int mb = m0 + wm * 64 + mr * 16 + 4 * g;
#pragma unroll
      for (int r = 0; r < 4; r++) {
        const int m = mb + r;
        const int b = m >> 10, n = m & 1023;
        const int bh = b * NH + h;
        const float v = acc[mr][nr][r];
        if (which == 0)      Qb[(size_t)(bh * 1024 + n) * 64 + d] = f2bf(v * 0.125f);
        else if (which == 1) Kb[(size_t)(bh * 1024 + n) * 64 + d] = f2bf(v);
        else                 Vt[(size_t)(bh * 64 + d) * 1024 + n] = f2bf(v);
      }
    }
  }
}

// ---------------- Kernel 2: flash attention ------------------------------
// One wave = 16 q rows. S^T = K*Q^T (swapped) so lane holds P[q=l&15][k].
// K-row permutation (m -> 8*(m>>2)+(m&3)) aligns the two QK^T outputs with
// the 8-contiguous-k A-fragment layout of the PV 16x16x32 MFMA.
__global__ __launch_bounds__(256) void k_attn(const ushort* __restrict__ Qb,
                                              const ushort* __restrict__ Kb,
                                              const ushort* __restrict__ Vt,
                                              ushort* __restrict__ Ab) {
  const int bh = blockIdx.x;
  const int tid = threadIdx.x;
  const int w = tid >> 6, l = tid & 63, g = l >> 4, c15 = l & 15;
  const int q0 = blockIdx.y * 64 + w * 16;
  const size_t rowbase = (size_t)bh * 1024;

  bf16x8 qf0, qf1;
  {
    const ushort* qp = Qb + (rowbase + q0 + c15) * 64 + g * 8;
    qf0 = *(const bf16x8*)qp;
    qf1 = *(const bf16x8*)(qp + 32);
  }
  const int perm = ((c15 >> 2) << 3) | (c15 & 3);
  const ushort* vbase = Vt + ((size_t)bh * 64 + c15) * 1024 + g * 8;

  float m_run = -1e30f, l_run = 0.0f;
  f32x4 o[4] = {};

  for (int kt = 0; kt < 1024; kt += 32) {
    const ushort* kp = Kb + (rowbase + kt + perm) * 64 + g * 8;
    bf16x8 ka0a = *(const bf16x8*)kp;
    bf16x8 ka0b = *(const bf16x8*)(kp + 32);
    bf16x8 ka1a = *(const bf16x8*)(kp + 256);  // rows perm+4
    bf16x8 ka1b = *(const bf16x8*)(kp + 288);
    f32x4 s0 = {0.f, 0.f, 0.f, 0.f};
    f32x4 s1 = {0.f, 0.f, 0.f, 0.f};
    s0 = mfma32(ka0a, qf0, s0);
    s0 = mfma32(ka0b, qf1, s0);
    s1 = mfma32(ka1a, qf0, s1);
    s1 = mfma32(ka1b, qf1, s1);
    // s0[r]: k = kt + 8g + r ; s1[r]: k = kt + 8g + 4 + r ; q = c15

    float tmax = fmaxf(fmaxf(fmaxf(s0[0], s0[1]), fmaxf(s0[2], s0[3])),
                       fmaxf(fmaxf(s1[0], s1[1]), fmaxf(s1[2], s1[3])));
    tmax = fmaxf(tmax, __shfl_xor(tmax, 16));
    tmax = fmaxf(tmax, __shfl_xor(tmax, 32));
    const float m_new = fmaxf(m_run, tmax);
    const float alpha = __expf(m_run - m_new);
    float p[8], psum = 0.f;
#pragma unroll
    for (int r = 0; r < 4; r++) { p[r] = __expf(s0[r] - m_new); psum += p[r]; }
#pragma unroll
    for (int r = 0; r < 4; r++) { p[4 + r] = __expf(s1[r] - m_new); psum += p[4 + r]; }
    psum += __shfl_xor(psum, 16);
    psum += __shfl_xor(psum, 32);
    l_run = l_run * alpha + psum;
    m_run = m_new;

    bf16x8 pa;
#pragma unroll
    for (int j = 0; j < 8; j++) pa[j] = (short)f2bf(p[j]);

    float av[4];
#pragma unroll
    for (int r = 0; r < 4; r++) av[r] = __shfl(alpha, 4 * g + r);
#pragma unroll
    for (int dt = 0; dt < 4; dt++) {
      bf16x8 vb = *(const bf16x8*)(vbase + kt + dt * 16 * 1024);
      f32x4 t = o[dt];
#pragma unroll
      for (int r = 0; r < 4; r++) t[r] *= av[r];
      o[dt] = mfma32(pa, vb, t);
    }
  }

  const float invl = 1.0f / l_run;
  float iv[4];
#pragma unroll
  for (int r = 0; r < 4; r++) iv[r] = __shfl(invl, 4 * g + r);
  const int b = bh / NH, h = bh % NH;
#pragma unroll
  for (int dt = 0; dt < 4; dt++)
#pragma unroll
    for (int r = 0; r < 4; r++) {
      const int n = q0 + 4 * g + r;
      Ab[(size_t)(b * 1024 + n) * 768 + h * 64 + dt * 16 + c15] =
          f2bf(o[dt][r] * iv[r]);
    }
}

// ---------------- Kernel 3: output projection ----------------------------
// Out[8192,768] = Ab[8192,768] * Wp[768,768]^T + bias   (fp32 out, fp32 bias)
__global__ __launch_bounds__(256) void k_proj(const ushort* __restrict__ Ain,
                                              const ushort* __restrict__ W,
                                              const float* __restrict__ Bp,
                                              float* __restrict__ Out) {
  __shared__ __align__(16) ushort As[128 * 32];
  __shared__ __align__(16) ushort Bs[128 * 32];
  const int m0 = blockIdx.y * 128;
  const int n0 = blockIdx.x * 128;
  const int tid = threadIdx.x;
  const int w = tid >> 6, l = tid & 63, g = l >> 4, c15 = l & 15;
  const int wm = w >> 1, wn = w & 1;

  f32x4 acc[4][4] = {};

  const int soff = w * 1024 + l * 16;
  const int e0 = soff >> 1;
  const int row0 = e0 >> 5, col0 = e0 & 31;
  const int e1 = (soff + 4096) >> 1;
  const int row1 = e1 >> 5, col1 = e1 & 31;

  for (int k0 = 0; k0 < 768; k0 += 32) {
    gl_lds16(Ain + (size_t)(m0 + row0) * 768 + k0 + col0, (char*)As + soff);
    gl_lds16(Ain + (size_t)(m0 + row1) * 768 + k0 + col1, (char*)As + soff + 4096);
    gl_lds16(W + (size_t)(n0 + row0) * 768 + k0 + col0, (char*)Bs + soff);
    gl_lds16(W + (size_t)(n0 + row1) * 768 + k0 + col1, (char*)Bs + soff + 4096);
    __syncthreads();
    bf16x8 af[4], bfr[4];
#pragma unroll
    for (int i = 0; i < 4; i++) {
      af[i]  = *(const bf16x8*)&As[(wm * 64 + i * 16 + c15) * 32 + g * 8];
      bfr[i] = *(const bf16x8*)&Bs[(wn * 64 + i * 16 + c15) * 32 + g * 8];
    }
#pragma unroll
    for (int mr = 0; mr < 4; mr++)
#pragma unroll
      for (int nr = 0; nr < 4; nr++)
        acc[mr][nr] = mfma32(af[mr], bfr[nr], acc[mr][nr]);
    __syncthreads();
  }

#pragma unroll
  for (int nr = 0; nr < 4; nr++) {
    const int cc = n0 + wn * 64 + nr * 16 + c15;
    const float bias = Bp[cc];
#pragma unroll
    for (int mr = 0; mr < 4; mr++) {
      const int mb = m0 + wm * 64 + mr * 16 + 4 * g;
#pragma unroll
      for (int r = 0; r < 4; r++) {
        const int m = mb + r;
        Out[(size_t)m * 768 + cc] = acc[mr][nr][r] + bias;
      }
    }
  }
}

extern "C" void kernel_launch(void* const* d_in, const int* in_sizes, int n_in,
                              void* d_out, int out_size, void* d_ws, size_t ws_size,
                              hipStream_t stream) {
  const float* X  = (const float*)d_in[0];   // [8,1024,768] fp32
  const float* Wq = (const float*)d_in[1];   // [2304,768] fp32
  const float* Wp = (const float*)d_in[2];   // [768,768] fp32
  const float* Bp = (const float*)d_in[3];   // [768] fp32
  float* Out = (float*)d_out;                // [8,1024,768] fp32

  char* ws = (char*)d_ws;
  const size_t SZ = (size_t)96 * 1024 * 64 * sizeof(ushort);  // 12.58 MB
  ushort* Qb  = (ushort*)(ws);            // [96][1024][64]  (pre-scaled by 1/8)
  ushort* Kb  = (ushort*)(ws + SZ);       // [96][1024][64]
  ushort* Vt  = (ushort*)(ws + 2 * SZ);   // [96][64][1024]  (transposed)
  ushort* Ab  = (ushort*)(ws + 3 * SZ);   // [8192][768]
  ushort* Xb  = (ushort*)(ws + 4 * SZ);   // [8192][768] bf16 of X
  ushort* Wqb = (ushort*)(ws + 5 * SZ);                  // [2304][768]
  ushort* Wpb = (ushort*)(ws + 5 * SZ + 2304 * 768 * 2); // [768][768]

  const int nX = 8192 * 768 / 4, nWq = 2304 * 768 / 4, nWp = 768 * 768 / 4;
  k_cvt<<<(nX + 255) / 256, 256, 0, stream>>>((const float4*)X, (ushort4*)Xb, nX);
  k_cvt<<<(nWq + 255) / 256, 256, 0, stream>>>((const float4*)Wq, (ushort4*)Wqb, nWq);
  k_cvt<<<(nWp + 255) / 256, 256, 0, stream>>>((const float4*)Wp, (ushort4*)Wpb, nWp);

  k_qkv<<<dim3(18, 64), 256, 0, stream>>>(Xb, Wqb, Qb, Kb, Vt);
  k_attn<<<dim3(96, 16), 256, 0, stream>>>(Qb, Kb, Vt, Ab);
  k_proj<<<dim3(6, 64), 256, 0, stream>>>(Ab, Wpb, Bp, Out);
}

// Round 3
// 187.625 us; speedup vs baseline: 1.7455x; 1.7455x over previous
//
#include <hip/hip_runtime.h>
#include <hip/hip_bf16.h>
#include <stdint.h>

// MHA: B=8, N=1024, DIM=768, H=12, D=64.  I/O fp32; internal bf16 MFMA.
#define NH 12

typedef __attribute__((ext_vector_type(8))) short bf16x8;
typedef __attribute__((ext_vector_type(4))) float f32x4;

static __device__ __forceinline__ ushort f2bf(float f) {
  union { float f; uint32_t u; } v; v.f = f;
  uint32_t r = (v.u + 0x7FFFu + ((v.u >> 16) & 1u)) >> 16;
  return (ushort)r;
}

static __device__ __forceinline__ void gl_lds16(const void* g, void* l) {
  __builtin_amdgcn_global_load_lds(
      (const __attribute__((address_space(1))) uint32_t*)(uintptr_t)g,
      (__attribute__((address_space(3))) uint32_t*)(uintptr_t)l,
      16, 0, 0);
}

static __device__ __forceinline__ f32x4 mfma32(bf16x8 a, bf16x8 b, f32x4 c) {
  return __builtin_amdgcn_mfma_f32_16x16x32_bf16(a, b, c, 0, 0, 0);
}

// ---------------- Kernel 0: fp32 -> bf16 convert -------------------------
__global__ __launch_bounds__(256) void k_cvt(const float4* __restrict__ src,
                                             ushort4* __restrict__ dst, int n4) {
  int i = blockIdx.x * blockDim.x + threadIdx.x;
  if (i < n4) {
    float4 v = src[i];
    ushort4 o;
    o.x = f2bf(v.x); o.y = f2bf(v.y); o.z = f2bf(v.z); o.w = f2bf(v.w);
    dst[i] = o;
  }
}

// ---------------- Kernel 1: QKV projection -------------------------------
// C[8192,2304] = X[8192,768] * Wqkv[2304,768]^T.
// Column c -> (h,d,which): c = h*192 + d*3 + which (0=q,1=k,2=v).
// K and V are scattered into MFMA *fragment order* so k_attn's loads are
// perfectly coalesced (addr = base + lane*8):
//   Kf[bh][t][i][lane][e]: i=2*s+hi; k-row kk=8x+y+4s (x=c15>>2,y=c15&3),
//                          d = hi*32 + g*8 + e, lane = g*16+c15
//   Vf[bh][t][dt][lane][e]: k = t*32 + g*8 + e, d = dt*16 + c15
__global__ __launch_bounds__(256) void k_qkv(const ushort* __restrict__ X,
                                             const ushort* __restrict__ W,
                                             ushort* __restrict__ Qb,
                                             ushort* __restrict__ Kf,
                                             ushort* __restrict__ Vf) {
  __shared__ __align__(16) ushort As[128 * 32];
  __shared__ __align__(16) ushort Bs[128 * 32];
  const int m0 = blockIdx.y * 128;
  const int n0 = blockIdx.x * 128;
  const int tid = threadIdx.x;
  const int w = tid >> 6, l = tid & 63, g = l >> 4, c15 = l & 15;
  const int wm = w >> 1, wn = w & 1;

  f32x4 acc[4][4] = {};

  const int soff = w * 1024 + l * 16;   // byte offset within 8KB tile
  const int e0 = soff >> 1;
  const int row0 = e0 >> 5, col0 = e0 & 31;
  const int e1 = (soff + 4096) >> 1;
  const int row1 = e1 >> 5, col1 = e1 & 31;

  for (int k0 = 0; k0 < 768; k0 += 32) {
    gl_lds16(X + (size_t)(m0 + row0) * 768 + k0 + col0, (char*)As + soff);
    gl_lds16(X + (size_t)(m0 + row1) * 768 + k0 + col1, (char*)As + soff + 4096);
    gl_lds16(W + (size_t)(n0 + row0) * 768 + k0 + col0, (char*)Bs + soff);
    gl_lds16(W + (size_t)(n0 + row1) * 768 + k0 + col1, (char*)Bs + soff + 4096);
    __syncthreads();
    bf16x8 af[4], bfr[4];
#pragma unroll
    for (int i = 0; i < 4; i++) {
      af[i]  = *(const bf16x8*)&As[(wm * 64 + i * 16 + c15) * 32 + g * 8];
      bfr[i] = *(const bf16x8*)&Bs[(wn * 64 + i * 16 + c15) * 32 + g * 8];
    }
#pragma unroll
    for (int mr = 0; mr < 4; mr++)
#pragma unroll
      for (int nr = 0; nr < 4; nr++)
        acc[mr][nr] = mfma32(af[mr], bfr[nr], acc[mr][nr]);
    __syncthreads();
  }

  // Epilogue: C/D layout col = lane&15, row = (lane>>4)*4 + r  [m89]
#pragma unroll
  for (int nr = 0; nr < 4; nr++) {
    const int cc = n0 + wn * 64 + nr * 16 + c15;
    const int hd = cc / 3;
    const int which = cc - hd * 3;
    const int d = hd & 63, h = hd >> 6;
    // d-derived fragment coords (K)
    const int gk = (d >> 3) & 3, ek = d & 7, hi = d >> 5;
    // d-derived fragment coords (V)
    const int dtv = d >> 4, cv = d & 15;
#pragma unroll
    for (int mr = 0; mr < 4; mr++) {
      const int mb = m0 + wm * 64 + mr * 16 + 4 * g;
#pragma unroll
      for (int r = 0; r < 4; r++) {
        const int m = mb + r;
        const int b = m >> 10, n = m & 1023;
        const int bh = b * NH + h;
        const float v = acc[mr][nr][r];
        if (which == 0) {
          Qb[(size_t)(bh * 1024 + n) * 64 + d] = f2bf(v * 0.125f);
        } else if (which == 1) {
          const int t = n >> 5, kk = n & 31;
          const int x = kk >> 3, s = (kk >> 2) & 1, y = kk & 3;
          const int lane = gk * 16 + (x * 4 + y);
          const int i = 2 * s + hi;
          Kf[(((size_t)bh * 32 + t) * 4 + i) * 512 + lane * 8 + ek] = f2bf(v);
        } else {
          const int t = n >> 5, kk = n & 31;
          const int gv = kk >> 3, ev = kk & 7;
          const int lane = gv * 16 + cv;
          Vf[(((size_t)bh * 32 + t) * 4 + dtv) * 512 + lane * 8 + ev] = f2bf(v);
        }
      }
    }
  }
}

// ---------------- Kernel 2: flash attention ------------------------------
// One wave = 16 q rows. S^T = K*Q^T so lane holds P[q=l&15][k].
// K/V come pre-permuted in fragment order: every load is base + l*8
// (1KB/wave coalesced). No LDS, no barriers -> compiler pipelines loads.
__global__ __launch_bounds__(256) void k_attn(const ushort* __restrict__ Qb,
                                              const ushort* __restrict__ Kf,
                                              const ushort* __restrict__ Vf,
                                              ushort* __restrict__ Ab) {
  const int bh = blockIdx.x;
  const int tid = threadIdx.x;
  const int w = tid >> 6, l = tid & 63, g = l >> 4, c15 = l & 15;
  const int q0 = blockIdx.y * 64 + w * 16;

  bf16x8 qf0, qf1;
  {
    const ushort* qp = Qb + ((size_t)bh * 1024 + q0 + c15) * 64 + g * 8;
    qf0 = *(const bf16x8*)qp;
    qf1 = *(const bf16x8*)(qp + 32);
  }
  const ushort* kfb = Kf + (size_t)bh * 32 * 2048 + l * 8;
  const ushort* vfb = Vf + (size_t)bh * 32 * 2048 + l * 8;

  float m_run = -1e30f, l_part = 0.0f;
  f32x4 o[4] = {};

  for (int t = 0; t < 32; t++) {
    const ushort* kp = kfb + t * 2048;
    bf16x8 ka0a = *(const bf16x8*)(kp);
    bf16x8 ka0b = *(const bf16x8*)(kp + 512);
    bf16x8 ka1a = *(const bf16x8*)(kp + 1024);
    bf16x8 ka1b = *(const bf16x8*)(kp + 1536);
    f32x4 s0 = {0.f, 0.f, 0.f, 0.f};
    f32x4 s1 = {0.f, 0.f, 0.f, 0.f};
    s0 = mfma32(ka0a, qf0, s0);
    s0 = mfma32(ka0b, qf1, s0);
    s1 = mfma32(ka1a, qf0, s1);
    s1 = mfma32(ka1b, qf1, s1);
    // s0[r]: k = 32t + 8g + r ; s1[r]: k = 32t + 8g + 4 + r ; q = c15

    float tmax = fmaxf(fmaxf(fmaxf(s0[0], s0[1]), fmaxf(s0[2], s0[3])),
                       fmaxf(fmaxf(s1[0], s1[1]), fmaxf(s1[2], s1[3])));
    tmax = fmaxf(tmax, __shfl_xor(tmax, 16));
    tmax = fmaxf(tmax, __shfl_xor(tmax, 32));

    // defer-max (T13): only rescale when max grows by > 8
    if (__ballot(tmax > m_run + 8.0f)) {
      const float m_new = fmaxf(m_run, tmax);
      const float alpha = __expf(m_run - m_new);
      float av[4];
#pragma unroll
      for (int r = 0; r < 4; r++) av[r] = __shfl(alpha, 4 * g + r);
      l_part *= alpha;
#pragma unroll
      for (int dt = 0; dt < 4; dt++)
#pragma unroll
        for (int r = 0; r < 4; r++) o[dt][r] *= av[r];
      m_run = m_new;
    }

    float p[8], psum = 0.f;
#pragma unroll
    for (int r = 0; r < 4; r++) { p[r] = __expf(s0[r] - m_run); psum += p[r]; }
#pragma unroll
    for (int r = 0; r < 4; r++) { p[4 + r] = __expf(s1[r] - m_run); psum += p[4 + r]; }
    l_part += psum;   // cross-lane (g) reduction deferred to after the loop

    bf16x8 pa;
#pragma unroll
    for (int j = 0; j < 8; j++) pa[j] = (short)f2bf(p[j]);

    const ushort* vp = vfb + t * 2048;
#pragma unroll
    for (int dt = 0; dt < 4; dt++) {
      bf16x8 vb = *(const bf16x8*)(vp + dt * 512);
      o[dt] = mfma32(pa, vb, o[dt]);
    }
  }

  float l_run = l_part;
  l_run += __shfl_xor(l_run, 16);
  l_run += __shfl_xor(l_run, 32);
  const float invl = 1.0f / l_run;
  float iv[4];
#pragma unroll
  for (int r = 0; r < 4; r++) iv[r] = __shfl(invl, 4 * g + r);
  const int b = bh / NH, h = bh % NH;
#pragma unroll
  for (int dt = 0; dt < 4; dt++)
#pragma unroll
    for (int r = 0; r < 4; r++) {
      const int n = q0 + 4 * g + r;
      Ab[(size_t)(b * 1024 + n) * 768 + h * 64 + dt * 16 + c15] =
          f2bf(o[dt][r] * iv[r]);
    }
}

// ---------------- Kernel 3: output projection ----------------------------
// Out[8192,768] = Ab[8192,768] * Wp[768,768]^T + bias   (fp32 out/bias)
__global__ __launch_bounds__(256) void k_proj(const ushort* __restrict__ Ain,
                                              const ushort* __restrict__ W,
                                              const float* __restrict__ Bp,
                                              float* __restrict__ Out) {
  __shared__ __align__(16) ushort As[128 * 32];
  __shared__ __align__(16) ushort Bs[128 * 32];
  const int m0 = blockIdx.y * 128;
  const int n0 = blockIdx.x * 128;
  const int tid = threadIdx.x;
  const int w = tid >> 6, l = tid & 63, g = l >> 4, c15 = l & 15;
  const int wm = w >> 1, wn = w & 1;

  f32x4 acc[4][4] = {};

  const int soff = w * 1024 + l * 16;
  const int e0 = soff >> 1;
  const int row0 = e0 >> 5, col0 = e0 & 31;
  const int e1 = (soff + 4096) >> 1;
  const int row1 = e1 >> 5, col1 = e1 & 31;

  for (int k0 = 0; k0 < 768; k0 += 32) {
    gl_lds16(Ain + (size_t)(m0 + row0) * 768 + k0 + col0, (char*)As + soff);
    gl_lds16(Ain + (size_t)(m0 + row1) * 768 + k0 + col1, (char*)As + soff + 4096);
    gl_lds16(W + (size_t)(n0 + row0) * 768 + k0 + col0, (char*)Bs + soff);
    gl_lds16(W + (size_t)(n0 + row1) * 768 + k0 + col1, (char*)Bs + soff + 4096);
    __syncthreads();
    bf16x8 af[4], bfr[4];
#pragma unroll
    for (int i = 0; i < 4; i++) {
      af[i]  = *(const bf16x8*)&As[(wm * 64 + i * 16 + c15) * 32 + g * 8];
      bfr[i] = *(const bf16x8*)&Bs[(wn * 64 + i * 16 + c15) * 32 + g * 8];
    }
#pragma unroll
    for (int mr = 0; mr < 4; mr++)
#pragma unroll
      for (int nr = 0; nr < 4; nr++)
        acc[mr][nr] = mfma32(af[mr], bfr[nr], acc[mr][nr]);
    __syncthreads();
  }

#pragma unroll
  for (int nr = 0; nr < 4; nr++) {
    const int cc = n0 + wn * 64 + nr * 16 + c15;
    const float bias = Bp[cc];
#pragma unroll
    for (int mr = 0; mr < 4; mr++) {
      const int mb = m0 + wm * 64 + mr * 16 + 4 * g;
#pragma unroll
      for (int r = 0; r < 4; r++) {
        const int m = mb + r;
        Out[(size_t)m * 768 + cc] = acc[mr][nr][r] + bias;
      }
    }
  }
}

extern "C" void kernel_launch(void* const* d_in, const int* in_sizes, int n_in,
                              void* d_out, int out_size, void* d_ws, size_t ws_size,
                              hipStream_t stream) {
  const float* X  = (const float*)d_in[0];   // [8,1024,768] fp32
  const float* Wq = (const float*)d_in[1];   // [2304,768] fp32
  const float* Wp = (const float*)d_in[2];   // [768,768] fp32
  const float* Bp = (const float*)d_in[3];   // [768] fp32
  float* Out = (float*)d_out;                // [8,1024,768] fp32

  char* ws = (char*)d_ws;
  const size_t SZ = (size_t)96 * 1024 * 64 * sizeof(ushort);  // 12.58 MB
  ushort* Qb  = (ushort*)(ws);            // [96][1024][64] (pre-scaled 1/8)
  ushort* Kf  = (ushort*)(ws + SZ);       // [96][32][4][64][8] fragment order
  ushort* Vf  = (ushort*)(ws + 2 * SZ);   // [96][32][4][64][8] fragment order
  ushort* Ab  = (ushort*)(ws + 3 * SZ);   // [8192][768]
  ushort* Xb  = (ushort*)(ws + 4 * SZ);   // [8192][768] bf16 of X
  ushort* Wqb = (ushort*)(ws + 5 * SZ);                  // [2304][768]
  ushort* Wpb = (ushort*)(ws + 5 * SZ + 2304 * 768 * 2); // [768][768]

  const int nX = 8192 * 768 / 4, nWq = 2304 * 768 / 4, nWp = 768 * 768 / 4;
  k_cvt<<<(nX + 255) / 256, 256, 0, stream>>>((const float4*)X, (ushort4*)Xb, nX);
  k_cvt<<<(nWq + 255) / 256, 256, 0, stream>>>((const float4*)Wq, (ushort4*)Wqb, nWq);
  k_cvt<<<(nWp + 255) / 256, 256, 0, stream>>>((const float4*)Wp, (ushort4*)Wpb, nWp);

  k_qkv<<<dim3(18, 64), 256, 0, stream>>>(Xb, Wqb, Qb, Kf, Vf);
  k_attn<<<dim3(96, 16), 256, 0, stream>>>(Qb, Kf, Vf, Ab);
  k_proj<<<dim3(6, 64), 256, 0, stream>>>(Ab, Wpb, Bp, Out);
}